// Round 1
// baseline (456.249 us; speedup 1.0000x reference)
//
#include <hip/hip_runtime.h>
#include <hip/hip_bf16.h>

#define BATCH 8
#define HH 256
#define WW 256
#define CI 64
#define CO 64
#define STYLE_IN 512

typedef __bf16 bf16x8 __attribute__((ext_vector_type(8)));
typedef float  f32x4  __attribute__((ext_vector_type(4)));

// round-to-nearest-even fp32 -> bf16 (inputs are finite normals)
static __device__ inline unsigned short f2bf(float f) {
    union { float f; unsigned int u; } a; a.f = f;
    unsigned int u = a.u;
    u += 0x7fffu + ((u >> 16) & 1u);
    return (unsigned short)(u >> 16);
}

// ---------------------------------------------------------------------------
// Kernel 1: EqualLinear modulation + demodulation -> bf16 weights
// Output layout: wbf[b][tap][co][ci], tap = kh*3+kw, ci contiguous.
// ---------------------------------------------------------------------------
__global__ __launch_bounds__(256) void modulate_kernel(
    const float* __restrict__ style, const float* __restrict__ mod_weight,
    const float* __restrict__ mod_bias, const float* __restrict__ weight,
    unsigned short* __restrict__ wbf)
{
    const int b = blockIdx.x;
    const int t = threadIdx.x;
    __shared__ float sp[4][64];
    __shared__ float s_mod[64];
    __shared__ float dpart[64][4];
    __shared__ float demod[64];

    const float LIN_SCALE  = 0.044194173824159216f;  // 1/sqrt(512)
    const float CONV_SCALE = 0.041666666666666664f;  // 1/sqrt(64*9)

    // s[ci] = sum_j style[b][j] * mw[j][ci] * LIN_SCALE + bias[ci]
    {
        const int ci = t & 63, part = t >> 6;   // 4 partials per ci
        float acc = 0.f;
        const float* st = style + b * STYLE_IN + part * 128;
        const float* mw = mod_weight + part * 128 * 64 + ci;
        #pragma unroll 8
        for (int j = 0; j < 128; ++j) acc += st[j] * mw[j * 64];
        sp[part][ci] = acc;
    }
    __syncthreads();
    if (t < 64)
        s_mod[t] = (sp[0][t] + sp[1][t] + sp[2][t] + sp[3][t]) * LIN_SCALE + mod_bias[t];
    __syncthreads();

    // demod[co] = rsqrt(sum_{ci,kh,kw} (CONV_SCALE*weight*s[ci])^2 + 1e-8)
    {
        const int co = t >> 2, part = t & 3;    // 4 partials per co, 144 elems each
        float acc = 0.f;
        const float* wp = weight + co * 576 + part * 144;
        for (int e = 0; e < 144; ++e) {
            int ee = part * 144 + e;            // flat = ci*9 + kh*3 + kw
            float v = CONV_SCALE * wp[e] * s_mod[ee / 9];
            acc += v * v;
        }
        dpart[co][part] = acc;
    }
    __syncthreads();
    if (t < 64)
        demod[t] = rsqrtf(dpart[t][0] + dpart[t][1] + dpart[t][2] + dpart[t][3] + 1e-8f);
    __syncthreads();

    // write wbf[b][tap][co][ci]
    for (int i = t; i < 9 * 64 * 64; i += 256) {
        int ci  = i & 63;
        int co  = (i >> 6) & 63;
        int tap = i >> 12;
        float v = CONV_SCALE * weight[co * 576 + ci * 9 + tap] * s_mod[ci] * demod[co];
        wbf[((b * 9 + tap) * 64 + co) * 64 + ci] = f2bf(v);
    }
}

// ---------------------------------------------------------------------------
// Kernel 2: implicit-GEMM conv. One workgroup: 1 (b,y) row x 128 px x 64 co.
// LDS: 3 input rows, 130-px halo, bf16, pixel stride 72 (144 B -> conflict-free
// ds_read_b128 A-fragments). 4 waves split M (32 px each), all N=64.
// ---------------------------------------------------------------------------
#define PXS   72          // pixel stride, bf16 elements (64 + 8 pad)
#define ROWPX 132         // padded pixels per LDS row (need 130)

__global__ __launch_bounds__(256) void conv_kernel(
    const float* __restrict__ x, const unsigned short* __restrict__ wbf,
    float* __restrict__ out)
{
    __shared__ unsigned short xs[3 * ROWPX * PXS];   // 57,024 B

    const int tid = threadIdx.x;
    const int xt  = blockIdx.x;      // 0..1  (x-tile of 128)
    const int y   = blockIdx.y;      // 0..255
    const int b   = blockIdx.z;      // 0..7
    const int x0  = xt * 128;

    // zero-fill LDS (covers SAME-padding halo)
    {
        int4* p = (int4*)xs;
        for (int i = tid; i < (3 * ROWPX * PXS * 2) / 16; i += 256)
            p[i] = make_int4(0, 0, 0, 0);
    }
    __syncthreads();

    // stage 3 rows (y-1..y+1), cols x0-1 .. x0+128, fp32 -> bf16
    for (int r = 0; r < 3; ++r) {
        int yin = y - 1 + r;
        if (yin < 0 || yin >= HH) continue;
        const float* src = x + ((size_t)(b * HH + yin) * WW) * CI;
        for (int i = tid; i < 130 * 16; i += 256) {
            int px = i >> 4;             // 0..129, lds pixel
            int cg = i & 15;             // float4 channel group
            int xin = x0 - 1 + px;
            if (xin < 0 || xin >= WW) continue;
            float4 v = *(const float4*)(src + xin * CI + cg * 4);
            ushort4 u;
            u.x = f2bf(v.x); u.y = f2bf(v.y); u.z = f2bf(v.z); u.w = f2bf(v.w);
            *(ushort4*)(&xs[(r * ROWPX + px) * PXS + cg * 4]) = u;
        }
    }
    __syncthreads();

    const int wave = tid >> 6, lane = tid & 63;
    const int lm = lane & 15, lq = lane >> 4;
    const int p0 = wave * 32;

    f32x4 acc[2][4];
    #pragma unroll
    for (int mi = 0; mi < 2; ++mi)
        #pragma unroll
        for (int ni = 0; ni < 4; ++ni)
            acc[mi][ni] = (f32x4){0.f, 0.f, 0.f, 0.f};

    const unsigned short* wb = wbf + (size_t)b * 9 * 64 * 64;

    for (int tap = 0; tap < 9; ++tap) {
        const int kh = tap / 3, kw = tap % 3;
        #pragma unroll
        for (int ks = 0; ks < 2; ++ks) {
            bf16x8 a[2];
            #pragma unroll
            for (int mi = 0; mi < 2; ++mi) {
                int px = p0 + mi * 16 + lm + kw;   // lds px = p + kw
                a[mi] = *(const bf16x8*)&xs[(kh * ROWPX + px) * PXS + ks * 32 + lq * 8];
            }
            #pragma unroll
            for (int ni = 0; ni < 4; ++ni) {
                int co = ni * 16 + lm;
                bf16x8 bfr = *(const bf16x8*)&wb[((size_t)(tap * 64 + co)) * 64 + ks * 32 + lq * 8];
                #pragma unroll
                for (int mi = 0; mi < 2; ++mi)
                    acc[mi][ni] = __builtin_amdgcn_mfma_f32_16x16x32_bf16(
                        a[mi], bfr, acc[mi][ni], 0, 0, 0);
            }
        }
    }

    // epilogue: C/D layout col = lane&15 (co), row = (lane>>4)*4 + reg (pixel)
    float* op = out + ((size_t)(b * HH + y) * WW + x0) * CO;
    #pragma unroll
    for (int mi = 0; mi < 2; ++mi)
        #pragma unroll
        for (int ni = 0; ni < 4; ++ni) {
            int co = ni * 16 + lm;
            #pragma unroll
            for (int r = 0; r < 4; ++r) {
                int p = p0 + mi * 16 + lq * 4 + r;
                op[(size_t)p * CO + co] = acc[mi][ni][r];
            }
        }
}

// ---------------------------------------------------------------------------
extern "C" void kernel_launch(void* const* d_in, const int* in_sizes, int n_in,
                              void* d_out, int out_size, void* d_ws, size_t ws_size,
                              hipStream_t stream) {
    const float* inputs     = (const float*)d_in[0];   // [8,256,256,64]
    const float* style      = (const float*)d_in[1];   // [8,512]
    const float* mod_weight = (const float*)d_in[2];   // [512,64]
    const float* mod_bias   = (const float*)d_in[3];   // [64]
    const float* weight     = (const float*)d_in[4];   // [1,64,64,3,3]
    float* out = (float*)d_out;
    unsigned short* wbf = (unsigned short*)d_ws;       // [8][9][64][64] bf16 = 589,824 B

    modulate_kernel<<<BATCH, 256, 0, stream>>>(style, mod_weight, mod_bias, weight, wbf);
    conv_kernel<<<dim3(2, HH, BATCH), 256, 0, stream>>>(inputs, wbf, out);
}

// Round 2
// 400.869 us; speedup vs baseline: 1.1382x; 1.1382x over previous
//
#include <hip/hip_runtime.h>

#define BATCH 8
#define HH 256
#define WW 256
#define CI 64
#define CO 64
#define STYLE_IN 512

typedef __bf16 bf16x8 __attribute__((ext_vector_type(8)));
typedef float  f32x4  __attribute__((ext_vector_type(4)));
typedef unsigned short u16x8 __attribute__((ext_vector_type(8)));

// round-to-nearest-even fp32 -> bf16
static __device__ inline unsigned short f2bf(float f) {
    union { float f; unsigned int u; } a; a.f = f;
    unsigned int u = a.u;
    u += 0x7fffu + ((u >> 16) & 1u);
    return (unsigned short)(u >> 16);
}

// ---------------------------------------------------------------------------
// Kernel 1: EqualLinear modulation + demodulation -> bf16 weights
// Output layout: wbf[b][tap][co][ci], tap = kh*3+kw, ci contiguous.
// ---------------------------------------------------------------------------
__global__ __launch_bounds__(256) void modulate_kernel(
    const float* __restrict__ style, const float* __restrict__ mod_weight,
    const float* __restrict__ mod_bias, const float* __restrict__ weight,
    unsigned short* __restrict__ wbf)
{
    const int b = blockIdx.x;
    const int t = threadIdx.x;
    __shared__ float sp[4][64];
    __shared__ float s_mod[64];
    __shared__ float dpart[64][4];
    __shared__ float demod[64];

    const float LIN_SCALE  = 0.044194173824159216f;  // 1/sqrt(512)
    const float CONV_SCALE = 0.041666666666666664f;  // 1/sqrt(64*9)

    // s[ci] = sum_j style[b][j] * mw[j][ci] * LIN_SCALE + bias[ci]
    {
        const int ci = t & 63, part = t >> 6;   // 4 partials per ci
        float acc = 0.f;
        const float* st = style + b * STYLE_IN + part * 128;
        const float* mw = mod_weight + part * 128 * 64 + ci;
        #pragma unroll 8
        for (int j = 0; j < 128; ++j) acc += st[j] * mw[j * 64];
        sp[part][ci] = acc;
    }
    __syncthreads();
    if (t < 64)
        s_mod[t] = (sp[0][t] + sp[1][t] + sp[2][t] + sp[3][t]) * LIN_SCALE + mod_bias[t];
    __syncthreads();

    // demod[co] = rsqrt(sum_{ci,kh,kw} (CONV_SCALE*weight*s[ci])^2 + 1e-8)
    {
        const int co = t >> 2, part = t & 3;    // 4 partials x (16 ci x 9 taps)
        float acc = 0.f;
        const float* wp = weight + co * 576 + part * 144;
        #pragma unroll
        for (int ci2 = 0; ci2 < 16; ++ci2) {
            float s = s_mod[part * 16 + ci2];
            #pragma unroll
            for (int tp = 0; tp < 9; ++tp) {
                float v = wp[ci2 * 9 + tp] * s;
                acc += v * v;
            }
        }
        dpart[co][part] = acc * (CONV_SCALE * CONV_SCALE);
    }
    __syncthreads();
    if (t < 64)
        demod[t] = rsqrtf(dpart[t][0] + dpart[t][1] + dpart[t][2] + dpart[t][3] + 1e-8f);
    __syncthreads();

    // write wbf[b][tap][co][ci]
    for (int i = t; i < 9 * 64 * 64; i += 256) {
        int ci  = i & 63;
        int co  = (i >> 6) & 63;
        int tap = i >> 12;
        float v = CONV_SCALE * weight[co * 576 + ci * 9 + tap] * s_mod[ci] * demod[co];
        wbf[((b * 9 + tap) * 64 + co) * 64 + ci] = f2bf(v);
    }
}

// ---------------------------------------------------------------------------
// Kernel 2: implicit-GEMM conv, strip-mined y with 4-row LDS ring buffer.
// One block: 128-px x-tile x 8 output rows x 64 co. Grid 2x32x8 = 512 blocks
// = exactly 2 resident/CU (LDS 74,880 B). Per row: prefetch next input row
// to regs -> MFMA compute from ring -> cvt+ds_write into slot 2 ahead ->
// single barrier. Row yin lives at slot (yin+1)&3.
// ---------------------------------------------------------------------------
#define PXS 72                      // pixel stride in bf16 elems (64 + 8 pad)
#define ROWPX 130                   // 128 + 2 halo
#define ROW_ELEMS (ROWPX * PXS)     // 9360 shorts = 18,720 B per row

__global__ __launch_bounds__(256, 2) void conv_kernel(
    const float* __restrict__ x, const unsigned short* __restrict__ wbf,
    float* __restrict__ out)
{
    __shared__ unsigned short xs[4 * ROW_ELEMS];   // 74,880 B

    const int tid = threadIdx.x;
    const int x0  = blockIdx.x * 128;
    const int y0  = blockIdx.y * 8;       // multiple of 8 -> slot math uses &3
    const int b   = blockIdx.z;

    // --- staging helpers: 1040 items/row (px 0..129, 8-ch groups), 5 iters ---
    auto issue = [&](int yin, f32x4* v) {
        const bool rok = (unsigned)yin < (unsigned)HH;
        const float* src = x + ((size_t)(b * HH + (rok ? yin : 0))) * WW * CI;
        #pragma unroll
        for (int k = 0; k < 5; ++k) {
            int i  = tid + k * 256;
            int px = i >> 3, cg = i & 7;
            int xin = x0 - 1 + px;
            bool ok = rok && ((unsigned)xin < (unsigned)WW) && (i < 1040);
            const float* p = src + (size_t)xin * CI + cg * 8;
            f32x4 z = {0.f, 0.f, 0.f, 0.f};
            v[2 * k]     = ok ? *(const f32x4*)p       : z;
            v[2 * k + 1] = ok ? *(const f32x4*)(p + 4) : z;
        }
    };
    auto commit = [&](int slot, const f32x4* v) {
        unsigned short* dst = xs + slot * ROW_ELEMS;
        #pragma unroll
        for (int k = 0; k < 5; ++k) {
            int i = tid + k * 256;
            if (k == 4 && i >= 1040) continue;
            int px = i >> 3, cg = i & 7;
            u16x8 u;
            #pragma unroll
            for (int e = 0; e < 4; ++e) {
                u[e]     = f2bf(v[2 * k][e]);
                u[e + 4] = f2bf(v[2 * k + 1][e]);
            }
            *(u16x8*)&dst[px * PXS + cg * 8] = u;
        }
    };

    // initial staging: rows y0-1, y0, y0+1 -> slots 0,1,2
    {
        f32x4 v[10];
        issue(y0 - 1, v); commit(0, v);
        issue(y0,     v); commit(1, v);
        issue(y0 + 1, v); commit(2, v);
    }
    __syncthreads();

    const int wave = tid >> 6, lane = tid & 63;
    const int lm = lane & 15, lq = lane >> 4;
    const int p0 = wave * 32;
    const unsigned short* wlane =
        wbf + (size_t)b * 9 * 4096 + (size_t)lm * 64 + lq * 8;
    const int aoff_lane = (p0 + lm) * PXS + lq * 8;

    for (int j = 0; j < 8; ++j) {
        const int y = y0 + j;

        // prefetch input row y+2 into registers (overlaps with MFMA below)
        f32x4 v[10];
        issue(y + 2, v);

        f32x4 acc[2][4];
        #pragma unroll
        for (int mi = 0; mi < 2; ++mi)
            #pragma unroll
            for (int ni = 0; ni < 4; ++ni)
                acc[mi][ni] = (f32x4){0.f, 0.f, 0.f, 0.f};

        // ring slots for input rows y-1, y, y+1
        const unsigned short* bases[3] = {
            xs + ((y)     & 3) * ROW_ELEMS,
            xs + ((y + 1) & 3) * ROW_ELEMS,
            xs + ((y + 2) & 3) * ROW_ELEMS,
        };

        #pragma unroll
        for (int kh = 0; kh < 3; ++kh) {
            const unsigned short* bs = bases[kh] + aoff_lane;
            #pragma unroll
            for (int kw = 0; kw < 3; ++kw) {
                #pragma unroll
                for (int ks = 0; ks < 2; ++ks) {
                    bf16x8 a0 = *(const bf16x8*)(bs + (kw)      * PXS + ks * 32);
                    bf16x8 a1 = *(const bf16x8*)(bs + (16 + kw) * PXS + ks * 32);
                    #pragma unroll
                    for (int ni = 0; ni < 4; ++ni) {
                        bf16x8 bfr = *(const bf16x8*)(wlane
                            + (kh * 3 + kw) * 4096 + ni * 1024 + ks * 32);
                        acc[0][ni] = __builtin_amdgcn_mfma_f32_16x16x32_bf16(
                            a0, bfr, acc[0][ni], 0, 0, 0);
                        acc[1][ni] = __builtin_amdgcn_mfma_f32_16x16x32_bf16(
                            a1, bfr, acc[1][ni], 0, 0, 0);
                    }
                }
            }
        }

        // write prefetched row y+2 into slot (y+3)&3 (disjoint from slots read)
        commit((y + 3) & 3, v);

        // epilogue: C/D layout col = lane&15 (co), row = (lane>>4)*4+reg (px)
        float* op = out + ((size_t)(b * HH + y) * WW + x0) * CO;
        #pragma unroll
        for (int mi = 0; mi < 2; ++mi)
            #pragma unroll
            for (int ni = 0; ni < 4; ++ni) {
                int co = ni * 16 + lm;
                #pragma unroll
                for (int r = 0; r < 4; ++r) {
                    int p = p0 + mi * 16 + lq * 4 + r;
                    op[(size_t)p * CO + co] = acc[mi][ni][r];
                }
            }

        __syncthreads();
    }
}

// ---------------------------------------------------------------------------
extern "C" void kernel_launch(void* const* d_in, const int* in_sizes, int n_in,
                              void* d_out, int out_size, void* d_ws, size_t ws_size,
                              hipStream_t stream) {
    const float* inputs     = (const float*)d_in[0];   // [8,256,256,64]
    const float* style      = (const float*)d_in[1];   // [8,512]
    const float* mod_weight = (const float*)d_in[2];   // [512,64]
    const float* mod_bias   = (const float*)d_in[3];   // [64]
    const float* weight     = (const float*)d_in[4];   // [1,64,64,3,3]
    float* out = (float*)d_out;
    unsigned short* wbf = (unsigned short*)d_ws;       // [8][9][64][64] bf16

    modulate_kernel<<<BATCH, 256, 0, stream>>>(style, mod_weight, mod_bias, weight, wbf);
    conv_kernel<<<dim3(2, 32, BATCH), 256, 0, stream>>>(inputs, wbf, out);
}

// Round 3
// 389.281 us; speedup vs baseline: 1.1720x; 1.0298x over previous
//
#include <hip/hip_runtime.h>

#define BATCH 8
#define HH 256
#define WW 256
#define CI 64
#define CO 64
#define STYLE_IN 512

typedef __bf16 bf16x8 __attribute__((ext_vector_type(8)));
typedef float  f32x4  __attribute__((ext_vector_type(4)));
typedef unsigned short u16x8 __attribute__((ext_vector_type(8)));

// round-to-nearest-even fp32 -> bf16
static __device__ inline unsigned short f2bf(float f) {
    union { float f; unsigned int u; } a; a.f = f;
    unsigned int u = a.u;
    u += 0x7fffu + ((u >> 16) & 1u);
    return (unsigned short)(u >> 16);
}

// ---------------------------------------------------------------------------
// Kernel 1: EqualLinear modulation + demodulation -> bf16 weights
// Output layout: wbf[b][tap][co][ci], tap = kh*3+kw, ci contiguous.
// ---------------------------------------------------------------------------
__global__ __launch_bounds__(256) void modulate_kernel(
    const float* __restrict__ style, const float* __restrict__ mod_weight,
    const float* __restrict__ mod_bias, const float* __restrict__ weight,
    unsigned short* __restrict__ wbf)
{
    const int b = blockIdx.x;
    const int t = threadIdx.x;
    __shared__ float sp[4][64];
    __shared__ float s_mod[64];
    __shared__ float dpart[64][4];
    __shared__ float demod[64];

    const float LIN_SCALE  = 0.044194173824159216f;  // 1/sqrt(512)
    const float CONV_SCALE = 0.041666666666666664f;  // 1/sqrt(64*9)

    {
        const int ci = t & 63, part = t >> 6;   // 4 partials per ci
        float acc = 0.f;
        const float* st = style + b * STYLE_IN + part * 128;
        const float* mw = mod_weight + part * 128 * 64 + ci;
        #pragma unroll 8
        for (int j = 0; j < 128; ++j) acc += st[j] * mw[j * 64];
        sp[part][ci] = acc;
    }
    __syncthreads();
    if (t < 64)
        s_mod[t] = (sp[0][t] + sp[1][t] + sp[2][t] + sp[3][t]) * LIN_SCALE + mod_bias[t];
    __syncthreads();

    {
        const int co = t >> 2, part = t & 3;    // 4 partials x (16 ci x 9 taps)
        float acc = 0.f;
        const float* wp = weight + co * 576 + part * 144;
        #pragma unroll
        for (int ci2 = 0; ci2 < 16; ++ci2) {
            float s = s_mod[part * 16 + ci2];
            #pragma unroll
            for (int tp = 0; tp < 9; ++tp) {
                float v = wp[ci2 * 9 + tp] * s;
                acc += v * v;
            }
        }
        dpart[co][part] = acc * (CONV_SCALE * CONV_SCALE);
    }
    __syncthreads();
    if (t < 64)
        demod[t] = rsqrtf(dpart[t][0] + dpart[t][1] + dpart[t][2] + dpart[t][3] + 1e-8f);
    __syncthreads();

    for (int i = t; i < 9 * 64 * 64; i += 256) {
        int ci  = i & 63;
        int co  = (i >> 6) & 63;
        int tap = i >> 12;
        float v = CONV_SCALE * weight[co * 576 + ci * 9 + tap] * s_mod[ci] * demod[co];
        wbf[((b * 9 + tap) * 64 + co) * 64 + ci] = f2bf(v);
    }
}

// ---------------------------------------------------------------------------
// Kernel 2: implicit-GEMM conv, strip-mined y, 4-row LDS ring.
// Operand order: A = weights (m=co), B = pixels (n=px)  =>  C/D gives each
// lane 4 consecutive co -> f32x4 nontemporal stores (full-line coalescing,
// no L2 write-allocate). Epilogue AFTER the barrier so the pre-barrier
// vmcnt(0) drain never waits on output stores or fresh loads.
// ---------------------------------------------------------------------------
#define PXS 72                      // pixel stride in bf16 elems (64 + 8 pad)
#define ROWPX 130                   // 128 + 2 halo
#define ROW_ELEMS (ROWPX * PXS)     // 9360 shorts = 18,720 B per row

__global__ __launch_bounds__(256, 2) void conv_kernel(
    const float* __restrict__ x, const unsigned short* __restrict__ wbf,
    float* __restrict__ out)
{
    __shared__ unsigned short xs[4 * ROW_ELEMS];   // 74,880 B -> 2 blocks/CU

    const int tid = threadIdx.x;
    const int x0  = blockIdx.x * 128;
    const int y0  = blockIdx.y * 8;       // multiple of 8 -> slot math uses &3
    const int b   = blockIdx.z;

    // --- staging: 1040 items/row (px 0..129 x 8-ch groups of 8 floats) ---
    auto issue = [&](int yin, f32x4* v) {
        const bool rok = (unsigned)yin < (unsigned)HH;
        const float* src = x + ((size_t)(b * HH + (rok ? yin : 0))) * WW * CI;
        #pragma unroll
        for (int k = 0; k < 5; ++k) {
            int i  = tid + k * 256;
            int px = i >> 3, cg = i & 7;
            int xin = x0 - 1 + px;
            bool ok = rok && ((unsigned)xin < (unsigned)WW) && (i < 1040);
            const float* p = src + (size_t)xin * CI + cg * 8;
            f32x4 z = {0.f, 0.f, 0.f, 0.f};
            v[2 * k]     = ok ? *(const f32x4*)p       : z;
            v[2 * k + 1] = ok ? *(const f32x4*)(p + 4) : z;
        }
    };
    auto commit = [&](int slot, const f32x4* v) {
        unsigned short* dst = xs + slot * ROW_ELEMS;
        #pragma unroll
        for (int k = 0; k < 5; ++k) {
            int i = tid + k * 256;
            if (k == 4 && i >= 1040) continue;
            int px = i >> 3, cg = i & 7;
            u16x8 u;
            #pragma unroll
            for (int e = 0; e < 4; ++e) {
                u[e]     = f2bf(v[2 * k][e]);
                u[e + 4] = f2bf(v[2 * k + 1][e]);
            }
            *(u16x8*)&dst[px * PXS + cg * 8] = u;
        }
    };

    // prologue: rows y0-1, y0, y0+1 -> slots 0,1,2
    {
        f32x4 v[10];
        issue(y0 - 1, v); commit(0, v);
        issue(y0,     v); commit(1, v);
        issue(y0 + 1, v); commit(2, v);
    }
    __syncthreads();

    const int wave = tid >> 6, lane = tid & 63;
    const int lm = lane & 15, lq = lane >> 4;
    const int p0 = wave * 32;
    // weight fragment base: wbf[b][tap][co=ni*16+lm][ci=ks*32+lq*8]
    const unsigned short* wlane =
        wbf + (size_t)b * 9 * 4096 + (size_t)lm * 64 + lq * 8;
    const int aoff_lane = (p0 + lm) * PXS + lq * 8;

    f32x4 vbuf[2][10];
    issue(y0 + 2, vbuf[0]);       // after barrier: in flight over first MFMA

    #pragma unroll
    for (int j = 0; j < 8; ++j) {
        const int y = y0 + j;

        f32x4 acc[2][4];
        #pragma unroll
        for (int mi = 0; mi < 2; ++mi)
            #pragma unroll
            for (int ni = 0; ni < 4; ++ni)
                acc[mi][ni] = (f32x4){0.f, 0.f, 0.f, 0.f};

        const unsigned short* bases[3] = {
            xs + ((y)     & 3) * ROW_ELEMS,
            xs + ((y + 1) & 3) * ROW_ELEMS,
            xs + ((y + 2) & 3) * ROW_ELEMS,
        };

        #pragma unroll
        for (int kh = 0; kh < 3; ++kh) {
            const unsigned short* bs = bases[kh] + aoff_lane;
            #pragma unroll
            for (int kw = 0; kw < 3; ++kw) {
                #pragma unroll
                for (int ks = 0; ks < 2; ++ks) {
                    // B operand: pixels, n = px = lm
                    bf16x8 x0f = *(const bf16x8*)(bs + (kw)      * PXS + ks * 32);
                    bf16x8 x1f = *(const bf16x8*)(bs + (16 + kw) * PXS + ks * 32);
                    #pragma unroll
                    for (int ni = 0; ni < 4; ++ni) {
                        // A operand: weights, m = co = lm
                        bf16x8 wf = *(const bf16x8*)(wlane
                            + (kh * 3 + kw) * 4096 + ni * 1024 + ks * 32);
                        acc[0][ni] = __builtin_amdgcn_mfma_f32_16x16x32_bf16(
                            wf, x0f, acc[0][ni], 0, 0, 0);
                        acc[1][ni] = __builtin_amdgcn_mfma_f32_16x16x32_bf16(
                            wf, x1f, acc[1][ni], 0, 0, 0);
                    }
                }
            }
        }

        // write row y+2 (prefetched last iter) into slot (y+3)&3
        commit((y + 3) & 3, vbuf[j & 1]);

        __syncthreads();   // drains: ds_writes + loads that are an iter old

        // issue next row's loads immediately (in flight over epilogue + MFMA)
        if (j < 7) issue(y + 3, vbuf[(j + 1) & 1]);

        // epilogue: D col = lane&15 = px-in-group, row = lq*4+reg = co-in-group
        float* op = out + ((size_t)(b * HH + y) * WW + x0) * CO;
        #pragma unroll
        for (int mi = 0; mi < 2; ++mi) {
            int pix = p0 + mi * 16 + lm;
            #pragma unroll
            for (int ni = 0; ni < 4; ++ni)
                __builtin_nontemporal_store(acc[mi][ni],
                    (f32x4*)(op + (size_t)pix * CO + ni * 16 + lq * 4));
        }
    }
}

// ---------------------------------------------------------------------------
extern "C" void kernel_launch(void* const* d_in, const int* in_sizes, int n_in,
                              void* d_out, int out_size, void* d_ws, size_t ws_size,
                              hipStream_t stream) {
    const float* inputs     = (const float*)d_in[0];   // [8,256,256,64]
    const float* style      = (const float*)d_in[1];   // [8,512]
    const float* mod_weight = (const float*)d_in[2];   // [512,64]
    const float* mod_bias   = (const float*)d_in[3];   // [64]
    const float* weight     = (const float*)d_in[4];   // [1,64,64,3,3]
    float* out = (float*)d_out;
    unsigned short* wbf = (unsigned short*)d_ws;       // [8][9][64][64] bf16

    modulate_kernel<<<BATCH, 256, 0, stream>>>(style, mod_weight, mod_bias, weight, wbf);
    conv_kernel<<<dim3(2, 32, BATCH), 256, 0, stream>>>(inputs, wbf, out);
}